// Round 13
// baseline (177.434 us; speedup 1.0000x reference)
//
#include <hip/hip_runtime.h>
#include <hip/hip_fp16.h>

#define Bn   2
#define CIN  64
#define COUT 64
#define Hd   192
#define Wd   192
#define HWd  (Hd*Wd)
#define Kk   9
#define NCh  20
#define NCP  24             // padded LO channels (bf16, 48B rows)
#define NTILE 1152          // 64-px output tiles total

typedef __attribute__((ext_vector_type(8))) short short8;
typedef __attribute__((ext_vector_type(4))) float f32x4;

static __device__ __forceinline__ ushort f2bf(float f) {
    unsigned u = __float_as_uint(f);
    u += 0x7fffu + ((u >> 16) & 1u);        // round-to-nearest-even
    return (ushort)(u >> 16);
}
static __device__ __forceinline__ float bf2f(ushort v) {
    return __uint_as_float(((unsigned)v) << 16);
}
static __device__ __forceinline__ ushort f2h(float f) {
    return __half_as_ushort(__float2half_rn(f));
}
static __device__ __forceinline__ float h2f(ushort u) {
    return __half2float(__ushort_as_half(u));
}

// ---------------- kT: all layout transforms ----------------
__global__ __launch_bounds__(256) void kT(const float* __restrict__ x,
        const float* __restrict__ inLO, const float* __restrict__ outLO,
        const float* __restrict__ w, const float* __restrict__ off_w,
        ushort* __restrict__ xtb, ushort* __restrict__ inLOb,
        ushort* __restrict__ outLOb, ushort* __restrict__ wtb,
        ushort* __restrict__ owtb) {
    __shared__ float lds[20 * 257];
    int bid = blockIdx.x, tid = threadIdx.x;
    if (bid < 1152) {                       // x -> xtb [b][p][64] bf16
        int b = bid / 576, p0 = (bid % 576) * 64;
        const float* src = x + b * CIN * HWd + p0;
        #pragma unroll
        for (int r = 0; r < 16; ++r) {
            int e = r * 256 + tid;          // e = c*64 + p
            int c = e >> 6, p = e & 63;
            lds[c * 65 + p] = src[c * HWd + p];
        }
        __syncthreads();
        ushort* dst = xtb + ((size_t)(b * HWd + p0)) * 64;
        #pragma unroll
        for (int r = 0; r < 16; ++r) {
            int e = r * 256 + tid;          // e = p*64 + c
            int p = e >> 6, c = e & 63;
            dst[e] = f2bf(lds[c * 65 + p]);
        }
    } else if (bid < 1728) {                // LO -> bf16 [b][p][24]
        int q = bid - 1152;
        int t = q / 288; q %= 288;
        int b = q / 144, p0 = (q % 144) * 256;
        const float* src = (t == 0 ? inLO : outLO) + b * NCh * HWd + p0;
        ushort* dst = (t == 0 ? inLOb : outLOb) + ((size_t)(b * HWd + p0)) * NCP;
        #pragma unroll
        for (int r = 0; r < 20; ++r) {
            int e = r * 256 + tid;          // e = n*256 + p
            int n = e >> 8, p = e & 255;
            lds[n * 257 + p] = src[n * HWd + p];
        }
        __syncthreads();
        #pragma unroll
        for (int r = 0; r < 24; ++r) {
            int e = r * 256 + tid;          // e = p*24 + n
            int p = e / NCP, n = e - p * NCP;
            dst[e] = (n < NCh) ? f2bf(lds[n * 257 + p]) : (ushort)0;
        }
    } else if (bid < 1872) {                // weight -> wtb B-frag
        int f = (bid - 1728) * 256 + tid;   // [tap][nt4][kt2][lane64][e8]
        int e = f & 7, lane = (f >> 3) & 63;
        int kt = (f >> 9) & 1, nt = (f >> 10) & 3, tap = f >> 12;
        int o = nt * 16 + (lane & 15);
        int c = kt * 32 + (lane >> 4) * 8 + e;
        wtb[f] = f2bf(w[(o * CIN + c) * Kk + tap]);
    } else {                                // off_w -> owtb (oc padded to 32)
        int f = (bid - 1872) * 256 + tid;   // [tap][nt2][kt2][lane64][e8] = 18432
        if (f < 18432) {
            int e = f & 7, lane = (f >> 3) & 63;
            int kt = (f >> 9) & 1, nt = (f >> 10) & 1, tap = f >> 11;
            int oc = nt * 16 + (lane & 15);
            int c = kt * 32 + (lane >> 4) * 8 + e;
            owtb[f] = (oc < 18) ? f2bf(off_w[(oc * CIN + c) * Kk + tap]) : (ushort)0;
        }
    }
}

// ---------------- k1: offset conv as MFMA GEMM ----------------
__global__ __launch_bounds__(256) void k1_gemm(const ushort* __restrict__ xtb,
        const ushort* __restrict__ owtb, const float* __restrict__ off_b,
        float* __restrict__ off) {
    int tid = threadIdx.x, bid = blockIdx.x;
    int jt = bid % 3, i = (bid / 3) % Hd, b = bid / (3 * Hd);
    int j0 = jt * 64;
    int lane = tid & 63, wv = tid >> 6;
    int m = lane & 15;
    int ch8 = lane >> 4;
    int j = j0 + wv * 16 + m;
    const ushort* xb = xtb + (size_t)b * HWd * 64;

    float bv0 = off_b[m];
    float bv1 = (m < 2) ? off_b[16 + m] : 0.f;
    f32x4 acc0 = (f32x4){bv0, bv0, bv0, bv0};
    f32x4 acc1 = (f32x4){bv1, bv1, bv1, bv1};
    short8 zero8 = {0, 0, 0, 0, 0, 0, 0, 0};

    #pragma unroll
    for (int t = 0; t < 9; ++t) {
        int yy = i + t / 3 - 1;
        int xx = j + t % 3 - 1;
        bool ok = (yy >= 0) && (yy < Hd) && (xx >= 0) && (xx < Wd);
        int yc = min(max(yy, 0), Hd - 1), xc = min(max(xx, 0), Wd - 1);
        const ushort* rowp = xb + (size_t)(yc * Wd + xc) * 64 + ch8 * 8;
        short8 a0 = *(const short8*)rowp;
        short8 a1 = *(const short8*)(rowp + 32);
        a0 = ok ? a0 : zero8;
        a1 = ok ? a1 : zero8;
        const ushort* wb = owtb + ((size_t)t << 11);
        short8 b00 = *(const short8*)(wb + (lane << 3));
        short8 b01 = *(const short8*)(wb + 512 + (lane << 3));
        short8 b10 = *(const short8*)(wb + 1024 + (lane << 3));
        short8 b11 = *(const short8*)(wb + 1536 + (lane << 3));
        acc0 = __builtin_amdgcn_mfma_f32_16x16x32_bf16(a0, b00, acc0, 0, 0, 0);
        acc0 = __builtin_amdgcn_mfma_f32_16x16x32_bf16(a1, b01, acc0, 0, 0, 0);
        acc1 = __builtin_amdgcn_mfma_f32_16x16x32_bf16(a0, b10, acc1, 0, 0, 0);
        acc1 = __builtin_amdgcn_mfma_f32_16x16x32_bf16(a1, b11, acc1, 0, 0, 0);
    }

    int prow = j0 + wv * 16 + (lane >> 4) * 4;
    int oc = lane & 15;
    float* ob = off + (size_t)b * 18 * HWd + i * Wd;
    #pragma unroll
    for (int r = 0; r < 4; ++r)
        ob[oc * HWd + prow + r] = acc0[r];
    if (oc < 2) {
        #pragma unroll
        for (int r = 0; r < 4; ++r)
            ob[(16 + oc) * HWd + prow + r] = acc1[r];
    }
}

// ---------------- k2: mask + sample-record generation ----------------
__global__ __launch_bounds__(256) void k2_mask(const ushort* __restrict__ inLOb,
        const ushort* __restrict__ outLOb, const float* __restrict__ off,
        uint4* __restrict__ rec) {
    int t = blockIdx.x * 256 + threadIdx.x;     // (b,k,p)
    int p = t % HWd;
    int k = (t / HWd) % Kk;
    int b = t / (Kk * HWd);
    int j = p % Wd, i = p / Wd;
    float offy = off[(b * 18 + 2 * k) * HWd + p];
    float offx = off[(b * 18 + 2 * k + 1) * HWd + p];

    // ---- mask: border-clamped bilinear over inLO, dot with outLO ----
    float py = (float)(i + (k / 3)) + offy - 95.5f;
    float px = (float)(j + (k % 3)) + offx - 95.5f;
    py = fminf(fmaxf(py, 0.f), 191.f);
    px = fminf(fmaxf(px, 0.f), 191.f);
    float y0f = floorf(py), x0f = floorf(px);
    float ly = py - y0f, lx = px - x0f;
    int y0 = (int)y0f, x0 = (int)x0f;
    int y1 = min(y0 + 1, Hd - 1), x1 = min(x0 + 1, Wd - 1);
    float w00 = (1.f - ly) * (1.f - lx);
    float w01 = (1.f - ly) * lx;
    float w10 = ly * (1.f - lx);
    float w11 = ly * lx;
    const short8* L00 = (const short8*)(inLOb + (size_t)(b * HWd + y0 * Wd + x0) * NCP);
    const short8* L01 = (const short8*)(inLOb + (size_t)(b * HWd + y0 * Wd + x1) * NCP);
    const short8* L10 = (const short8*)(inLOb + (size_t)(b * HWd + y1 * Wd + x0) * NCP);
    const short8* L11 = (const short8*)(inLOb + (size_t)(b * HWd + y1 * Wd + x1) * NCP);
    const short8* O  = (const short8*)(outLOb + (size_t)(b * HWd + p) * NCP);
    float acc = 0.f;
    #pragma unroll
    for (int n3 = 0; n3 < 3; ++n3) {
        short8 a = L00[n3], bb = L01[n3], c = L10[n3], d = L11[n3], o = O[n3];
        #pragma unroll
        for (int e = 0; e < 8; ++e) {
            float s = w00 * bf2f((ushort)a[e]) + w01 * bf2f((ushort)bb[e])
                    + w10 * bf2f((ushort)c[e]) + w11 * bf2f((ushort)d[e]);
            acc += s * bf2f((ushort)o[e]);
        }
    }

    // ---- main-conv bilinear record (zero-pad semantics) ----
    float py2 = (float)(i - 1 + (k / 3)) + offy;
    float px2 = (float)(j - 1 + (k % 3)) + offx;
    float y0f2 = floorf(py2), x0f2 = floorf(px2);
    float ly2 = py2 - y0f2, lx2 = px2 - x0f2;
    int yA = (int)y0f2, xA = (int)x0f2;
    int yB = yA + 1, xB = xA + 1;
    bool vy0 = (yA >= 0 && yA < Hd), vy1 = (yB >= 0 && yB < Hd);
    bool vx0 = (xA >= 0 && xA < Wd), vx1 = (xB >= 0 && xB < Wd);
    float W00 = (vy0 && vx0) ? (1.f - ly2) * (1.f - lx2) * acc : 0.f;
    float W01 = (vy0 && vx1) ? (1.f - ly2) * lx2 * acc : 0.f;
    float W10 = (vy1 && vx0) ? ly2 * (1.f - lx2) * acc : 0.f;
    float W11 = (vy1 && vx1) ? ly2 * lx2 * acc : 0.f;
    int y0c = min(max(yA, 0), Hd - 1), y1c = min(max(yB, 0), Hd - 1);
    int x0c = min(max(xA, 0), Wd - 1), x1c = min(max(xB, 0), Wd - 1);
    uint4 r;
    r.x = (unsigned)y0c | ((unsigned)y1c << 16);
    r.y = (unsigned)x0c | ((unsigned)x1c << 16);
    r.z = (unsigned)f2h(W00) | ((unsigned)f2h(W01) << 16);
    r.w = (unsigned)f2h(W10) | ((unsigned)f2h(W11) << 16);
    rec[(size_t)(b * Kk + k) * HWd + p] = r;
}

// ---------------- k3: deformable conv, barrier-free per-wave MFMA ----------------
// Each wave owns 16 px x 64 out. Gathers use lane = kg*16+px so results land
// directly in MFMA A-fragment layout: no LDS, no __syncthreads.
__global__ __launch_bounds__(256, 4) void k3_part(const ushort* __restrict__ xtb,
        const uint4* __restrict__ rec, const ushort* __restrict__ wtb,
        ushort* __restrict__ part) {
    int tid = threadIdx.x;
    int bid = blockIdx.x;
    int h = bid >= NTILE;           // taps [0,5) or [5,9)
    int tb = bid - (h ? NTILE : 0);
    int t0 = h ? 5 : 0, t1 = h ? 9 : 5;
    int jt = tb % 3, i = (tb / 3) % Hd, b = tb / (3 * Hd);
    int j0 = jt * 64;

    int lane = tid & 63;
    int wv = tid >> 6;              // wave owns px [wv*16, wv*16+16)
    int px16 = lane & 15;           // A-frag row (pixel)
    int kg = lane >> 4;             // A-frag k-group (8 ch)
    const ushort* xb = xtb + (size_t)b * HWd * 64;

    f32x4 acc[4];
    #pragma unroll
    for (int nt = 0; nt < 4; ++nt) acc[nt] = (f32x4){0.f, 0.f, 0.f, 0.f};

    for (int t = t0; t < t1; ++t) {
        // per-pixel record (lanes with same px16 share one 16B record)
        const uint4* recb = rec + (size_t)(b * Kk + t) * HWd + i * Wd + j0 + wv * 16;
        uint4 rc = recb[px16];
        int y0 = rc.x & 0xffff, y1 = rc.x >> 16;
        int x0 = rc.y & 0xffff, x1 = rc.y >> 16;
        float w00 = h2f((ushort)(rc.z & 0xffff));
        float w01 = h2f((ushort)(rc.z >> 16));
        float w10 = h2f((ushort)(rc.w & 0xffff));
        float w11 = h2f((ushort)(rc.w >> 16));
        size_t r00 = (size_t)(y0 * Wd + x0) * 64;
        size_t r01 = (size_t)(y0 * Wd + x1) * 64;
        size_t r10 = (size_t)(y1 * Wd + x0) * 64;
        size_t r11 = (size_t)(y1 * Wd + x1) * 64;

        // A-fragments: gather straight into fragment layout
        short8 af[2];
        #pragma unroll
        for (int kt = 0; kt < 2; ++kt) {
            int co = kt * 32 + kg * 8;
            short8 g0 = *(const short8*)(xb + r00 + co);
            short8 g1 = *(const short8*)(xb + r01 + co);
            short8 g2 = *(const short8*)(xb + r10 + co);
            short8 g3 = *(const short8*)(xb + r11 + co);
            short8 pk;
            #pragma unroll
            for (int e = 0; e < 8; ++e) {
                float s = w00 * bf2f((ushort)g0[e]) + w01 * bf2f((ushort)g1[e])
                        + w10 * bf2f((ushort)g2[e]) + w11 * bf2f((ushort)g3[e]);
                pk[e] = (short)f2bf(s);
            }
            af[kt] = pk;
        }

        // 8 MFMA: n64 via 4 nt tiles x 2 kt
        #pragma unroll
        for (int nt = 0; nt < 4; ++nt) {
            short8 b0 = *(const short8*)(wtb + ((((t * 4 + nt) * 2 + 0) * 64 + lane) << 3));
            short8 b1 = *(const short8*)(wtb + ((((t * 4 + nt) * 2 + 1) * 64 + lane) << 3));
            acc[nt] = __builtin_amdgcn_mfma_f32_16x16x32_bf16(af[0], b0, acc[nt], 0, 0, 0);
            acc[nt] = __builtin_amdgcn_mfma_f32_16x16x32_bf16(af[1], b1, acc[nt], 0, 0, 0);
        }
    }

    // write partial tile bf16: part[(h*NTILE+tb)*4096 + o*64 + p]
    // D layout: col(o) = lane&15, row(px) = (lane>>4)*4 + reg
    ushort* pb = part + ((size_t)(h * NTILE + tb) << 12);
    int colo = lane & 15;
    int p0 = wv * 16 + (lane >> 4) * 4;
    #pragma unroll
    for (int nt = 0; nt < 4; ++nt) {
        int o = nt * 16 + colo;
        ushort4 s;
        s.x = f2bf(acc[nt][0]);
        s.y = f2bf(acc[nt][1]);
        s.z = f2bf(acc[nt][2]);
        s.w = f2bf(acc[nt][3]);
        *(ushort4*)(pb + o * 64 + p0) = s;
    }
}

// ---------------- k4: reduce bf16 halves + bias -> out ----------------
__global__ __launch_bounds__(256) void k4_reduce(const ushort* __restrict__ part,
        const float* __restrict__ bias, float* __restrict__ out) {
    int g = blockIdx.x * 256 + threadIdx.x;     // short8 index, NTILE*512 total
    int tile = g >> 9;
    int wi = g & 511;
    int o = wi >> 3;
    int p0 = (wi & 7) << 3;
    const short8* pp = (const short8*)part;
    short8 a = pp[g];
    short8 c = pp[g + NTILE * 512];
    float bv = bias[o];
    int jt = tile % 3, i = (tile / 3) % Hd, b = tile / (3 * Hd);
    float* op = out + ((size_t)(b * COUT + o) * HWd) + i * Wd + jt * 64 + p0;
    float4 r0, r1;
    r0.x = bf2f((ushort)a[0]) + bf2f((ushort)c[0]) + bv;
    r0.y = bf2f((ushort)a[1]) + bf2f((ushort)c[1]) + bv;
    r0.z = bf2f((ushort)a[2]) + bf2f((ushort)c[2]) + bv;
    r0.w = bf2f((ushort)a[3]) + bf2f((ushort)c[3]) + bv;
    r1.x = bf2f((ushort)a[4]) + bf2f((ushort)c[4]) + bv;
    r1.y = bf2f((ushort)a[5]) + bf2f((ushort)c[5]) + bv;
    r1.z = bf2f((ushort)a[6]) + bf2f((ushort)c[6]) + bv;
    r1.w = bf2f((ushort)a[7]) + bf2f((ushort)c[7]) + bv;
    *(float4*)op = r0;
    *(float4*)(op + 4) = r1;
}

extern "C" void kernel_launch(void* const* d_in, const int* in_sizes, int n_in,
                              void* d_out, int out_size, void* d_ws, size_t ws_size,
                              hipStream_t stream) {
    const float* x      = (const float*)d_in[0];
    const float* inLO   = (const float*)d_in[1];
    const float* outLO  = (const float*)d_in[2];
    const float* weight = (const float*)d_in[3];
    const float* bias   = (const float*)d_in[4];
    const float* off_w  = (const float*)d_in[5];
    const float* off_b  = (const float*)d_in[6];
    float* out = (float*)d_out;

    // workspace layout (rec first for 16B alignment)
    uint4*  rec    = (uint4*)d_ws;                          // 663552 * 16B
    ushort* part   = (ushort*)(rec + (size_t)Bn * Kk * HWd);// 2*1152*4096 bf16
    float*  off    = (float*)(part + (size_t)2 * NTILE * 4096); // 2*18*36864 f
    ushort* wtb    = (ushort*)(off + (size_t)Bn * 18 * HWd);    // 36864
    ushort* owtb   = wtb + 36864;                               // 18432
    ushort* xtb    = owtb + 18432;                              // 2*36864*64
    ushort* inLOb  = xtb + (size_t)Bn * HWd * CIN;              // 2*36864*24
    ushort* outLOb = inLOb + (size_t)Bn * HWd * NCP;

    kT<<<1944, 256, 0, stream>>>(x, inLO, outLO, weight, off_w,
                                 xtb, inLOb, outLOb, wtb, owtb);
    k1_gemm<<<NTILE, 256, 0, stream>>>(xtb, owtb, off_b, off);
    k2_mask<<<2592, 256, 0, stream>>>(inLOb, outLOb, off, rec);
    k3_part<<<2 * NTILE, 256, 0, stream>>>(xtb, rec, wtb, part);
    k4_reduce<<<2304, 256, 0, stream>>>(part, bias, out);
}